// Round 2
// baseline (1147.429 us; speedup 1.0000x reference)
//
#include <hip/hip_runtime.h>

// ConstructBaselineSuperEdge: B=8192, NM=ND=32 (N=64), NODE_F=EDGE_F=HID=256.
//
// Algebraic rewrite (exact):
//   scores_n = (e_n . (Wk @ q) + q.bk) / 16          -- avoids k projection
//   local    = (sum_n attn_n * e_n) @ Wv + bv        -- avoids v projection
// => kernel is HBM-bound on the 1.04 GB of neighbor features, read once.
//
// R1 change: phase 5 online-softmax batched 4 neighbors/iter
//   - 4 independent shuffle-reduce chains pipeline (was 1 serial chain/neighbor)
//   - rescale + running-max amortized 4x, exp2f domain (1 v_exp_f32 per exp)
//   - register double-buffer: 8 float4 loads in flight per lane (4x MLP)
//   - nontemporal loads for the 1 GB one-shot neighbor stream (protect L2)
// R2 fix: __builtin_nontemporal_load needs a native vector type, not
//   HIP_vector_type<float,4> — wrap via ext_vector_type(4).

typedef float f32x4_t __attribute__((ext_vector_type(4)));

static __device__ __forceinline__ float4 ntload4(const float4* p) {
    f32x4_t v = __builtin_nontemporal_load(reinterpret_cast<const f32x4_t*>(p));
    return make_float4(v.x, v.y, v.z, v.w);
}

constexpr int G = 8;   // batch elements per block

__global__ __launch_bounds__(256, 4)
void superedge_fused(const float* __restrict__ mnode0,
                     const float* __restrict__ mnode1,
                     const float* __restrict__ dnode0,
                     const float* __restrict__ dnode1,
                     const float* __restrict__ mrel0,
                     const float* __restrict__ drel0,
                     const float* __restrict__ W_edge,
                     const float* __restrict__ b_edge,
                     const float* __restrict__ Wq,
                     const float* __restrict__ bq,
                     const float* __restrict__ Wk,
                     const float* __restrict__ bk,
                     const float* __restrict__ Wv,
                     const float* __restrict__ bv,
                     float* __restrict__ out)
{
    __shared__ float sA[G * 512];   // pre_md, later reused: attn-weighted neighbor sum
    __shared__ float sK[G * 512];   // qk = Wk @ q  ([0:256]=rel rows, [256:512]=node rows)
    __shared__ float sC[G * 256];   // edge_emb, later reused: q

    const int t  = threadIdx.x;      // 256 threads = 4 waves
    const int b0 = blockIdx.x * G;

    // ---------- Phase 1: stage pre_md = [mnode0 || dnode0] ----------
    {
        const float4* m4 = reinterpret_cast<const float4*>(mnode0);
        const float4* d4 = reinterpret_cast<const float4*>(dnode0);
        float4* A4 = reinterpret_cast<float4*>(sA);
        #pragma unroll
        for (int idx = t; idx < G * 128; idx += 256) {
            const int g  = idx >> 7;
            const int i4 = idx & 127;
            A4[g * 128 + i4] = (i4 < 64) ? m4[(b0 + g) * 64 + i4]
                                         : d4[(b0 + g) * 64 + (i4 - 64)];
        }
    }
    __syncthreads();

    // ---------- Phase 2: edge_emb = relu(pre_md @ W_edge + b_edge) ----------
    // thread t owns output column t; LDS reads are wave-uniform (broadcast).
    float acc[G];
    #pragma unroll
    for (int g = 0; g < G; ++g) acc[g] = 0.f;
    #pragma unroll 4
    for (int i4 = 0; i4 < 128; ++i4) {
        const float w0 = W_edge[(i4 * 4 + 0) * 256 + t];
        const float w1 = W_edge[(i4 * 4 + 1) * 256 + t];
        const float w2 = W_edge[(i4 * 4 + 2) * 256 + t];
        const float w3 = W_edge[(i4 * 4 + 3) * 256 + t];
        #pragma unroll
        for (int g = 0; g < G; ++g) {
            const float4 a = reinterpret_cast<const float4*>(sA)[g * 128 + i4];
            acc[g] = fmaf(a.x, w0, fmaf(a.y, w1, fmaf(a.z, w2, fmaf(a.w, w3, acc[g]))));
        }
    }
    {
        const float be = b_edge[t];
        #pragma unroll
        for (int g = 0; g < G; ++g) {
            float e = acc[g] + be;
            e = e > 0.f ? e : 0.f;
            __builtin_nontemporal_store(e, &out[(size_t)(b0 + g) * 512 + t]); // output[:, 0:256]
            sC[g * 256 + t] = e;
        }
    }
    __syncthreads();

    // ---------- Phase 3: q = edge_emb @ Wq + bq ----------
    #pragma unroll
    for (int g = 0; g < G; ++g) acc[g] = 0.f;
    #pragma unroll 4
    for (int i4 = 0; i4 < 64; ++i4) {
        const float w0 = Wq[(i4 * 4 + 0) * 256 + t];
        const float w1 = Wq[(i4 * 4 + 1) * 256 + t];
        const float w2 = Wq[(i4 * 4 + 2) * 256 + t];
        const float w3 = Wq[(i4 * 4 + 3) * 256 + t];
        #pragma unroll
        for (int g = 0; g < G; ++g) {
            const float4 a = reinterpret_cast<const float4*>(sC)[g * 64 + i4];
            acc[g] = fmaf(a.x, w0, fmaf(a.y, w1, fmaf(a.z, w2, fmaf(a.w, w3, acc[g]))));
        }
    }
    const float bqv = bq[t];
    __syncthreads();   // all reads of edge_emb done before overwriting sC with q
    #pragma unroll
    for (int g = 0; g < G; ++g) sC[g * 256 + t] = acc[g] + bqv;
    __syncthreads();

    // ---------- Phase 4: qk = Wk @ q (rows i=t and i=t+256 per thread) ----------
    {
        float k0[G], k1[G];
        #pragma unroll
        for (int g = 0; g < G; ++g) { k0[g] = 0.f; k1[g] = 0.f; }
        const float4* Wk4 = reinterpret_cast<const float4*>(Wk);
        #pragma unroll 4
        for (int jj = 0; jj < 64; ++jj) {
            const float4 w0 = Wk4[t * 64 + jj];
            const float4 w1 = Wk4[(t + 256) * 64 + jj];
            #pragma unroll
            for (int g = 0; g < G; ++g) {
                const float4 qv = reinterpret_cast<const float4*>(sC)[g * 64 + jj];
                k0[g] = fmaf(w0.x, qv.x, fmaf(w0.y, qv.y, fmaf(w0.z, qv.z, fmaf(w0.w, qv.w, k0[g]))));
                k1[g] = fmaf(w1.x, qv.x, fmaf(w1.y, qv.y, fmaf(w1.z, qv.z, fmaf(w1.w, qv.w, k1[g]))));
            }
        }
        #pragma unroll
        for (int g = 0; g < G; ++g) {
            sK[g * 512 + t]       = k0[g];   // rel rows
            sK[g * 512 + 256 + t] = k1[g];   // node rows
        }
    }
    __syncthreads();

    // ---------- Phase 5: streaming attention, 4 neighbors per iteration ----------
    {
        const int wave = t >> 6;
        const int lane = t & 63;
        #pragma unroll
        for (int gg = 0; gg < 2; ++gg) {
            const int g  = wave * 2 + gg;
            const int bg = b0 + g;

            // sb = q . bk  (wave reduction)
            const float4 qv  = reinterpret_cast<const float4*>(sC + g * 256)[lane];
            const float4 bkv = reinterpret_cast<const float4*>(bk)[lane];
            float sb = qv.x * bkv.x + qv.y * bkv.y + qv.z * bkv.z + qv.w * bkv.w;
            #pragma unroll
            for (int off = 32; off >= 1; off >>= 1) sb += __shfl_xor(sb, off);

            const float4 kr = reinterpret_cast<const float4*>(sK + g * 512)[lane];
            const float4 kn = reinterpret_cast<const float4*>(sK + g * 512 + 256)[lane];

            const float4* mrel4 = reinterpret_cast<const float4*>(mrel0) + (size_t)bg * 2048;
            const float4* drel4 = reinterpret_cast<const float4*>(drel0) + (size_t)bg * 2048;
            const float4* mnod4 = reinterpret_cast<const float4*>(mnode1) + (size_t)bg * 2048;
            const float4* dnod4 = reinterpret_cast<const float4*>(dnode1) + (size_t)bg * 2048;

            // work in log2 domain: s2 = (p + sb)/16 * log2(e) = p*C + sb2
            const float C   = 0.0625f * 1.44269504088896f;
            const float sb2 = sb * C;

            float m2 = -3.0e38f, l = 0.f;
            float ar0 = 0, ar1 = 0, ar2 = 0, ar3 = 0;
            float an0 = 0, an1 = 0, an2 = 0, an3 = 0;

            // current batch (neighbors 0..3) — always from the m-side (4 | 32)
            float4 rc0 = ntload4(&mrel4[0 * 64 + lane]);
            float4 rc1 = ntload4(&mrel4[1 * 64 + lane]);
            float4 rc2 = ntload4(&mrel4[2 * 64 + lane]);
            float4 rc3 = ntload4(&mrel4[3 * 64 + lane]);
            float4 nc0 = ntload4(&mnod4[0 * 64 + lane]);
            float4 nc1 = ntload4(&mnod4[1 * 64 + lane]);
            float4 nc2 = ntload4(&mnod4[2 * 64 + lane]);
            float4 nc3 = ntload4(&mnod4[3 * 64 + lane]);

            #pragma unroll 2
            for (int it = 0; it < 16; ++it) {
                // prefetch next 4-neighbor batch (8 float4 in flight per lane)
                float4 rn0, rn1, rn2, rn3, nn0, nn1, nn2, nn3;
                if (it < 15) {
                    const int nb   = (it + 1) * 4;               // 4-batches never straddle 32
                    const float4* rs = (nb < 32) ? mrel4 : drel4;
                    const float4* ns = (nb < 32) ? mnod4 : dnod4;
                    const int base = (nb & 31) * 64 + lane;
                    rn0 = ntload4(&rs[base]);
                    rn1 = ntload4(&rs[base + 64]);
                    rn2 = ntload4(&rs[base + 128]);
                    rn3 = ntload4(&rs[base + 192]);
                    nn0 = ntload4(&ns[base]);
                    nn1 = ntload4(&ns[base + 64]);
                    nn2 = ntload4(&ns[base + 128]);
                    nn3 = ntload4(&ns[base + 192]);
                }

                // partial dots for 4 neighbors (independent chains)
                float p0 = rc0.x * kr.x + rc0.y * kr.y + rc0.z * kr.z + rc0.w * kr.w
                         + nc0.x * kn.x + nc0.y * kn.y + nc0.z * kn.z + nc0.w * kn.w;
                float p1 = rc1.x * kr.x + rc1.y * kr.y + rc1.z * kr.z + rc1.w * kr.w
                         + nc1.x * kn.x + nc1.y * kn.y + nc1.z * kn.z + nc1.w * kn.w;
                float p2 = rc2.x * kr.x + rc2.y * kr.y + rc2.z * kr.z + rc2.w * kr.w
                         + nc2.x * kn.x + nc2.y * kn.y + nc2.z * kn.z + nc2.w * kn.w;
                float p3 = rc3.x * kr.x + rc3.y * kr.y + rc3.z * kr.z + rc3.w * kr.w
                         + nc3.x * kn.x + nc3.y * kn.y + nc3.z * kn.z + nc3.w * kn.w;

                // 4 butterfly reduces, interleaved so the chains pipeline
                #pragma unroll
                for (int off = 32; off >= 1; off >>= 1) {
                    p0 += __shfl_xor(p0, off);
                    p1 += __shfl_xor(p1, off);
                    p2 += __shfl_xor(p2, off);
                    p3 += __shfl_xor(p3, off);
                }

                const float s0 = fmaf(p0, C, sb2);
                const float s1 = fmaf(p1, C, sb2);
                const float s2 = fmaf(p2, C, sb2);
                const float s3 = fmaf(p3, C, sb2);

                const float m2new = fmaxf(fmaxf(fmaxf(s0, s1), fmaxf(s2, s3)), m2);
                const float esc = exp2f(m2 - m2new);
                const float e0  = exp2f(s0 - m2new);
                const float e1  = exp2f(s1 - m2new);
                const float e2  = exp2f(s2 - m2new);
                const float e3  = exp2f(s3 - m2new);

                l = fmaf(l, esc, (e0 + e1) + (e2 + e3));
                ar0 = fmaf(ar0, esc, fmaf(e0, rc0.x, fmaf(e1, rc1.x, fmaf(e2, rc2.x, e3 * rc3.x))));
                ar1 = fmaf(ar1, esc, fmaf(e0, rc0.y, fmaf(e1, rc1.y, fmaf(e2, rc2.y, e3 * rc3.y))));
                ar2 = fmaf(ar2, esc, fmaf(e0, rc0.z, fmaf(e1, rc1.z, fmaf(e2, rc2.z, e3 * rc3.z))));
                ar3 = fmaf(ar3, esc, fmaf(e0, rc0.w, fmaf(e1, rc1.w, fmaf(e2, rc2.w, e3 * rc3.w))));
                an0 = fmaf(an0, esc, fmaf(e0, nc0.x, fmaf(e1, nc1.x, fmaf(e2, nc2.x, e3 * nc3.x))));
                an1 = fmaf(an1, esc, fmaf(e0, nc0.y, fmaf(e1, nc1.y, fmaf(e2, nc2.y, e3 * nc3.y))));
                an2 = fmaf(an2, esc, fmaf(e0, nc0.z, fmaf(e1, nc1.z, fmaf(e2, nc2.z, e3 * nc3.z))));
                an3 = fmaf(an3, esc, fmaf(e0, nc0.w, fmaf(e1, nc1.w, fmaf(e2, nc2.w, e3 * nc3.w))));
                m2 = m2new;

                if (it < 15) {
                    rc0 = rn0; rc1 = rn1; rc2 = rn2; rc3 = rn3;
                    nc0 = nn0; nc1 = nn1; nc2 = nn2; nc3 = nn3;
                }
            }

            const float inv = 1.f / l;
            reinterpret_cast<float4*>(sA + g * 512)[lane] =
                make_float4(ar0 * inv, ar1 * inv, ar2 * inv, ar3 * inv);
            reinterpret_cast<float4*>(sA + g * 512 + 256)[lane] =
                make_float4(an0 * inv, an1 * inv, an2 * inv, an3 * inv);
        }
    }
    __syncthreads();

    // ---------- Phase 6: local = wsum @ Wv + bv ----------
    #pragma unroll
    for (int g = 0; g < G; ++g) acc[g] = 0.f;
    #pragma unroll 4
    for (int i4 = 0; i4 < 128; ++i4) {
        const float w0 = Wv[(i4 * 4 + 0) * 256 + t];
        const float w1 = Wv[(i4 * 4 + 1) * 256 + t];
        const float w2 = Wv[(i4 * 4 + 2) * 256 + t];
        const float w3 = Wv[(i4 * 4 + 3) * 256 + t];
        #pragma unroll
        for (int g = 0; g < G; ++g) {
            const float4 a = reinterpret_cast<const float4*>(sA)[g * 128 + i4];
            acc[g] = fmaf(a.x, w0, fmaf(a.y, w1, fmaf(a.z, w2, fmaf(a.w, w3, acc[g]))));
        }
    }
    {
        const float bvv = bv[t];
        #pragma unroll
        for (int g = 0; g < G; ++g)
            __builtin_nontemporal_store(acc[g] + bvv,
                                        &out[(size_t)(b0 + g) * 512 + 256 + t]); // output[:, 256:512]
    }
}

extern "C" void kernel_launch(void* const* d_in, const int* in_sizes, int n_in,
                              void* d_out, int out_size, void* d_ws, size_t ws_size,
                              hipStream_t stream) {
    const float* mnode0 = (const float*)d_in[0];
    const float* mnode1 = (const float*)d_in[1];
    const float* dnode0 = (const float*)d_in[2];
    const float* dnode1 = (const float*)d_in[3];
    const float* mrel0  = (const float*)d_in[4];
    const float* drel0  = (const float*)d_in[5];
    const float* W_edge = (const float*)d_in[6];
    const float* b_edge = (const float*)d_in[7];
    const float* Wq     = (const float*)d_in[8];
    const float* bq     = (const float*)d_in[9];
    const float* Wk     = (const float*)d_in[10];
    const float* bk     = (const float*)d_in[11];
    const float* Wv     = (const float*)d_in[12];
    const float* bv     = (const float*)d_in[13];
    float* out = (float*)d_out;

    superedge_fused<<<dim3(8192 / G), dim3(256), 0, stream>>>(
        mnode0, mnode1, dnode0, dnode1, mrel0, drel0,
        W_edge, b_edge, Wq, bq, Wk, bk, Wv, bv, out);
}